// Round 16
// baseline (338.101 us; speedup 1.0000x reference)
//
#include <hip/hip_runtime.h>
#include <math.h>

#define NEGV -10000000.0f

constexpr int B_ = 8, T_ = 16;
constexpr int QALL = 256, QRES = 128, QARG = 192;
constexpr int STATE = 256, VOCAB = 10000;
constexpr int WT = 32;
constexpr int NWT = (VOCAB + WT - 1) / WT;   // 313
constexpr int JS = 4;                        // DP j-split (4 x 48-j windows)

// ---- workspace layout (units of 4 bytes) ----
constexpr size_t OFF_CHART = 0;                                    // chart[ell][s][b][a]
constexpr size_t CHART_SZ  = (size_t)T_ * T_ * B_ * QALL;          // 524288
constexpr size_t OFF_EGR   = OFF_CHART + CHART_SZ;                 // exp(G_rarg) [j][r]
constexpr size_t OFF_EGL   = OFF_EGR + (size_t)QARG * QRES;        // exp(G_larg) [j][r]
constexpr size_t OFF_LF    = OFF_EGL + (size_t)QARG * QRES;        // lfunc transposed [j][r] (int)
constexpr size_t OFF_RF    = OFF_LF + (size_t)QARG * QRES;         // rfunc transposed [j][r] (int)
constexpr size_t OFF_S0    = OFF_RF + (size_t)QARG * QRES;         // split[:,0] per a (256)
constexpr size_t OFF_S1    = OFF_S0 + QALL;                        // split[:,1] per a (256)
constexpr size_t OFF_LSE   = OFF_S1 + QALL;                        // emit row lse (256)
constexpr size_t OFF_PMIT  = OFF_LSE + QALL;                       // emit partial max [wt][a] (313*256)
constexpr size_t OFF_PSEM  = OFF_PMIT + (size_t)NWT * QALL;        // emit partial sum [wt][a] (313*256)
// DP partial ping-pong buffers OVERLAY the emit PM/PS region (dead after chart0).
constexpr int    PMAXP     = 704;
constexpr size_t OFF_P0S   = OFF_PMIT;                             // [704][128]
constexpr size_t OFF_P0M   = OFF_P0S + (size_t)PMAXP * QRES;       // [704]
constexpr size_t OFF_P1S   = OFF_P0M + PMAXP;
constexpr size_t OFF_P1M   = OFF_P1S + (size_t)PMAXP * QRES;
constexpr size_t OFF_OVEND = OFF_P1M + PMAXP;                      // end of overlay region
// raw emit scores for the 128 word positions [i][a].
// ROUND-15 BUG FIX: with NWT=313, PM/PS extends past the old OFF_P1S overlay slot,
// so RAW gets a DEDICATED region beyond BOTH overlays (no liveness conflict).
constexpr size_t OFF_RAW   = OFF_OVEND;                            // [128][256]
// total ~838k floats (~3.4 MB)

__device__ __forceinline__ size_t chIdx(int ell, int s, int b) {
    return OFF_CHART + ((size_t)((ell * 16 + s) * 8 + b)) * 256;
}

__device__ __forceinline__ float waveMax(float v) {
    #pragma unroll
    for (int m = 32; m >= 1; m >>= 1) v = fmaxf(v, __shfl_xor(v, m, 64));
    return v;
}
__device__ __forceinline__ float waveSum(float v) {
    #pragma unroll
    for (int m = 32; m >= 1; m >>= 1) v += __shfl_xor(v, m, 64);
    return v;
}
__device__ __forceinline__ float blockMax(float v, float* scr, int nw) {
    int lane = threadIdx.x & 63, w = threadIdx.x >> 6;
    v = waveMax(v);
    if (lane == 0) scr[w] = v;
    __syncthreads();
    float r = scr[0];
    for (int i = 1; i < nw; i++) r = fmaxf(r, scr[i]);
    __syncthreads();
    return r;
}
__device__ __forceinline__ float blockSum(float v, float* scr, int nw) {
    int lane = threadIdx.x & 63, w = threadIdx.x >> 6;
    v = waveSum(v);
    if (lane == 0) scr[w] = v;
    __syncthreads();
    float r = 0.f;
    for (int i = 0; i < nw; i++) r += scr[i];
    __syncthreads();
    return r;
}

// ---------------- G tables ----------------
__global__ __launch_bounds__(192) void prep_g_kernel(
        const float* __restrict__ rule_W, const float* __restrict__ rule_b,
        const float* __restrict__ assoc,
        const float* __restrict__ larg_mask, const float* __restrict__ rarg_mask,
        const int* __restrict__ lfunc, const int* __restrict__ rfunc,
        float* __restrict__ ws) {
    __shared__ float scr[4];
    int r = blockIdx.x;      // 0..127
    int j = threadIdx.x;     // 0..191
    float v0 = rule_W[r * 2 * QARG + j] + rule_b[j];
    float v1 = rule_W[r * 2 * QARG + QARG + j] + rule_b[QARG + j];
    float m = blockMax(fmaxf(v0, v1), scr, 3);
    float s = blockSum(expf(v0 - m) + expf(v1 - m), scr, 3);
    float l = m + logf(s);
    float av = assoc[r * QARG + j];
    float gl = v0 - l + av + larg_mask[r * QARG + j];
    float gr = v1 - l + av + rarg_mask[r * QARG + j];
    ws[OFF_EGL + (size_t)j * QRES + r] = expf(gl);
    ws[OFF_EGR + (size_t)j * QRES + r] = expf(gr);
    ((int*)ws)[OFF_LF + (size_t)j * QRES + r] = lfunc[r * QARG + j];
    ((int*)ws)[OFF_RF + (size_t)j * QRES + r] = rfunc[r * QARG + j];
}

// ---------------- split-score MLP (1024 threads, split-K x4) ----------------
#define MLP_MATVEC(INBUF, W, RES) do {                                          \
    float acc_ = 0.f;                                                           \
    _Pragma("unroll 16")                                                        \
    for (int s_ = 0; s_ < 64; s_++)                                             \
        acc_ += INBUF[s0 + s_] * W[(s0 + s_) * STATE + col];                    \
    part[t] = acc_;                                                             \
    __syncthreads();                                                            \
    RES = part[col] + part[STATE + col] + part[2 * STATE + col]                 \
        + part[3 * STATE + col];                                                \
} while (0)

__global__ __launch_bounds__(1024) void mlp_kernel(
        const float* __restrict__ nt_emb,
        const float* __restrict__ sw1, const float* __restrict__ sb1,
        const float* __restrict__ r1w1, const float* __restrict__ r1b1,
        const float* __restrict__ r1w2, const float* __restrict__ r1b2,
        const float* __restrict__ r2w1, const float* __restrict__ r2b1,
        const float* __restrict__ r2w2, const float* __restrict__ r2b2,
        const float* __restrict__ sw2, const float* __restrict__ sb2,
        float* __restrict__ ws) {
    __shared__ float xin[STATE], hbuf[STATE], tbuf[STATE];
    __shared__ float part[4 * STATE];
    __shared__ float scr[16];
    int a = blockIdx.x, t = threadIdx.x;
    int col = t & 255;
    int grp = t >> 8;
    int s0 = grp * 64;
    if (t < STATE) xin[t] = nt_emb[a * STATE + t];
    __syncthreads();
    float r;
    MLP_MATVEC(xin, sw1, r);
    if (grp == 0) hbuf[col] = r + sb1[col];
    __syncthreads();
    MLP_MATVEC(hbuf, r1w1, r);
    if (grp == 0) tbuf[col] = fmaxf(r + r1b1[col], 0.f);
    __syncthreads();
    MLP_MATVEC(tbuf, r1w2, r);
    if (grp == 0) hbuf[col] += fmaxf(r + r1b2[col], 0.f);
    __syncthreads();
    MLP_MATVEC(hbuf, r2w1, r);
    if (grp == 0) tbuf[col] = fmaxf(r + r2b1[col], 0.f);
    __syncthreads();
    MLP_MATVEC(tbuf, r2w2, r);
    if (grp == 0) hbuf[col] += fmaxf(r + r2b2[col], 0.f);
    __syncthreads();
    float hv = (t < STATE) ? hbuf[t] : 0.f;
    float v0 = (t < STATE) ? hv * sw2[t * 2 + 0] : 0.f;
    float v1 = (t < STATE) ? hv * sw2[t * 2 + 1] : 0.f;
    float u0 = blockSum(v0, scr, 16) + sb2[0];
    float u1 = blockSum(v1, scr, 16) + sb2[1];
    if (t == 0) {
        float mm = fmaxf(u0, u1);
        float l = mm + logf(expf(u0 - mm) + expf(u1 - mm));
        ws[OFF_S0 + a] = u0 - l;
        ws[OFF_S1 + a] = u1 - l;
    }
}

// ---------------- emit GEMM: WT=32 -> 1252 blocks (grid-limited occupancy fix) ----------------
// 64a x 32w tile, double-buffered LDS + register prefetch (1 barrier/k-step).
__global__ __launch_bounds__(256) void emit_kernel(
        const int* __restrict__ words,
        const float* __restrict__ nt_emb, const float* __restrict__ W_emit,
        const float* __restrict__ b_emit, float* __restrict__ ws) {
    __shared__ float As[2][16][64];     // [buf][kk][aa]
    __shared__ float Bs[2][16][WT];     // [buf][kk][ww]
    __shared__ float redM[64][8], redS[64][8];
    __shared__ int sw[128];
    int wt = blockIdx.x, at = blockIdx.y;
    int t = threadIdx.x;
    int tx = t & 7, ty = t >> 3;        // 8 w-groups x 32 a-groups
    if (t < 128) sw[t] = words[t];
    int wbase = wt * WT, abase = at * 64;
    int idx4 = t * 4;
    int akk = idx4 & 15, aaa = idx4 >> 4;    // A staging: float4 (akk multiple of 4)
    int idx2 = t * 2;
    int bkk = idx2 >> 5, bww = idx2 & 31;    // B staging: float2 (bww multiple of 2)
    const float* Aptr = &nt_emb[(size_t)(abase + aaa) * STATE + akk];
    int bw = wbase + bww;
    bool bfull = (bw + 1 < VOCAB);

    // prologue: stage k-tile 0 into buffer 0
    {
        float4 av = *(const float4*)(Aptr + 0);
        float2 bv;
        const float* src = &W_emit[(size_t)bkk * VOCAB + bw];
        if (bfull) bv = *(const float2*)src;
        else {
            bv.x = (bw + 0 < VOCAB) ? src[0] : 0.f;
            bv.y = (bw + 1 < VOCAB) ? src[1] : 0.f;
        }
        As[0][akk + 0][aaa] = av.x; As[0][akk + 1][aaa] = av.y;
        As[0][akk + 2][aaa] = av.z; As[0][akk + 3][aaa] = av.w;
        *(float2*)&Bs[0][bkk][bww] = bv;
    }
    __syncthreads();

    float acc[2][4];
    #pragma unroll
    for (int i = 0; i < 2; i++)
        #pragma unroll
        for (int j = 0; j < 4; j++) acc[i][j] = 0.f;

    for (int step = 0; step < 16; step++) {
        int cur = step & 1;
        float4 nav; float2 nbv;
        bool more = (step + 1 < 16);
        if (more) {   // issue next-tile loads BEFORE compute (hide latency)
            nav = *(const float4*)(Aptr + (step + 1) * 16);
            const float* src = &W_emit[(size_t)((step + 1) * 16 + bkk) * VOCAB + bw];
            if (bfull) nbv = *(const float2*)src;
            else {
                nbv.x = (bw + 0 < VOCAB) ? src[0] : 0.f;
                nbv.y = (bw + 1 < VOCAB) ? src[1] : 0.f;
            }
        }
        #pragma unroll
        for (int kk = 0; kk < 16; kk++) {
            float a2[2], b4[4];
            #pragma unroll
            for (int i = 0; i < 2; i++) a2[i] = As[cur][kk][ty * 2 + i];
            #pragma unroll
            for (int j = 0; j < 4; j++) b4[j] = Bs[cur][kk][tx * 4 + j];
            #pragma unroll
            for (int i = 0; i < 2; i++)
                #pragma unroll
                for (int j = 0; j < 4; j++) acc[i][j] += a2[i] * b4[j];
        }
        if (more) {
            int nb = cur ^ 1;
            As[nb][akk + 0][aaa] = nav.x; As[nb][akk + 1][aaa] = nav.y;
            As[nb][akk + 2][aaa] = nav.z; As[nb][akk + 3][aaa] = nav.w;
            *(float2*)&Bs[nb][bkk][bww] = nbv;
        }
        __syncthreads();
    }

    // epilogue: + b_emit
    float be[4];
    #pragma unroll
    for (int j = 0; j < 4; j++) {
        int w = wbase + tx * 4 + j;
        be[j] = (w < VOCAB) ? b_emit[w] : 0.f;
    }
    #pragma unroll
    for (int i = 0; i < 2; i++)
        #pragma unroll
        for (int j = 0; j < 4; j++) {
            int w = wbase + tx * 4 + j;
            if (w < VOCAB) acc[i][j] += be[j];
        }
    // capture word columns: raw[i2][a] = score(a, words[i2]) for words in this tile
    for (int i2 = 0; i2 < 128; i2++) {
        int loc = sw[i2] - wbase;
        if (loc >= 0 && loc < WT && (loc >> 2) == tx) {
            int j = loc & 3;
            #pragma unroll
            for (int i = 0; i < 2; i++)
                ws[OFF_RAW + (size_t)i2 * QALL + abase + ty * 2 + i] = acc[i][j];
        }
    }
    // per-row partial (max, sumexp) over the 32 w of this tile
    #pragma unroll
    for (int i = 0; i < 2; i++) {
        float mloc = -3.0e38f;
        #pragma unroll
        for (int j = 0; j < 4; j++) {
            int w = wbase + tx * 4 + j;
            if (w < VOCAB) mloc = fmaxf(mloc, acc[i][j]);
        }
        float sloc = 0.f;
        #pragma unroll
        for (int j = 0; j < 4; j++) {
            int w = wbase + tx * 4 + j;
            if (w < VOCAB) sloc += expf(acc[i][j] - mloc);
        }
        redM[ty * 2 + i][tx] = mloc;
        redS[ty * 2 + i][tx] = sloc;
    }
    __syncthreads();
    if (t < 64) {
        float M = -3.0e38f;
        #pragma unroll
        for (int i = 0; i < 8; i++) M = fmaxf(M, redM[t][i]);
        float S = 0.f;
        #pragma unroll
        for (int i = 0; i < 8; i++) S += redS[t][i] * expf(redM[t][i] - M);
        ws[OFF_PMIT + (size_t)wt * QALL + abase + t] = M;
        ws[OFF_PSEM + (size_t)wt * QALL + abase + t] = S;
    }
}

// ---------------- combine emit partials -> lse per row (one block per a, 2 partials/thread) ----------------
__global__ __launch_bounds__(256) void lse_kernel(float* __restrict__ ws) {
    __shared__ float scr[4];
    int a = blockIdx.x;
    int t = threadIdx.x;
    float m0 = (t < NWT)       ? ws[OFF_PMIT + (size_t)t * QALL + a]         : -3.0e38f;
    float m1 = (t + 256 < NWT) ? ws[OFF_PMIT + (size_t)(t + 256) * QALL + a] : -3.0e38f;
    float M = blockMax(fmaxf(m0, m1), scr, 4);
    float myS = 0.f;
    if (t < NWT)       myS += ws[OFF_PSEM + (size_t)t * QALL + a] * expf(m0 - M);
    if (t + 256 < NWT) myS += ws[OFF_PSEM + (size_t)(t + 256) * QALL + a] * expf(m1 - M);
    float S = blockSum(myS, scr, 4);
    if (t == 0) ws[OFF_LSE + a] = M + logf(S);
}

// ---------------- chart level 0: trivial assemble from captured raw scores ----------------
__global__ __launch_bounds__(256) void chart0_kernel(float* __restrict__ ws) {
    int blk = blockIdx.x;            // i2 = b*16 + tp
    int b = blk >> 4, tp = blk & 15;
    int a = threadIdx.x;
    float val = ws[OFF_RAW + (size_t)blk * QALL + a] - ws[OFF_LSE + a] + ws[OFF_S1 + a];
    ws[chIdx(0, tp, b) + a] = val;
}

// ---------------- per-level DP (templated on ELL; 4 main barriers, merged gather) ----------------
__device__ __forceinline__ void reconRow(float* row, const float* __restrict__ ws,
                                         size_t prevS, size_t prevM, int cellp, int KCp,
                                         const int* __restrict__ res2all) {
    int t = threadIdx.x;
    int np = JS * KCp;
    size_t base = (size_t)cellp * np;
    if (t < 256) row[t] = NEGV;
    float M = -3.0e38f;
    for (int p = 0; p < np; p++) M = fmaxf(M, ws[prevM + base + p]);
    __syncthreads();
    if (t < QRES) {
        float S = 0.f;
        for (int p = 0; p < np; p++)
            S += expf(ws[prevM + base + p] - M) * ws[prevS + (base + p) * QRES + t];
        row[res2all[t]] = logf(S) + M + ws[OFF_S0 + res2all[t]];
    }
    __syncthreads();
}

template<int ELL>
__global__ __launch_bounds__(512) void level_k(float* __restrict__ ws,
                                               const int* __restrict__ argpc,
                                               const int* __restrict__ res2all) {
    __shared__ __align__(16) float rowL[4][256], rowR[4][256];
    __shared__ __align__(16) float eB0[4][48], eB1[4][48];
    __shared__ float mLs[4], mRs[4];
    __shared__ float Sred[512];
    __shared__ float outrow[256];

    constexpr int K = ELL - 1;
    constexpr int KC = (K + 3) >> 2;
    constexpr int matCount = (ELL >= 3) ? (T_ - ELL + 2) * 8 : 0;
    constexpr int ellp = ELL - 1;
    constexpr int KCp = (ellp - 1 + 3) >> 2;
    constexpr size_t prevS = (ellp & 1) ? OFF_P1S : OFF_P0S;
    constexpr size_t prevM = (ellp & 1) ? OFF_P1M : OFF_P0M;
    constexpr size_t curS  = (ELL & 1) ? OFF_P1S : OFF_P0S;
    constexpr size_t curM  = (ELL & 1) ? OFF_P1M : OFF_P0M;

    int t = threadIdx.x;
    int bid = blockIdx.x;

    if (bid < matCount) {
        int cellp = bid;
        int sp = cellp >> 3, bp = cellp & 7;
        reconRow(outrow, ws, prevS, prevM, cellp, KCp, res2all);
        if (t < 256) ws[chIdx(ellp - 1, sp, bp) + t] = outrow[t];
        return;
    }

    int aid = bid - matCount;          // aid = ((cell*JS + jq)*KC + kc)
    int kc = aid % KC;
    int rem = aid / KC;
    int jq = rem & (JS - 1);
    int cell = rem >> 2;
    int s = cell >> 3, b = cell & 7;
    int k0 = kc * 4 + 1;
    int kn = min(4, K - kc * 4);
    int j0 = jq * 48;
    int side = t >> 8, u = t & 255;

    // 1. bulk-load materialized rows
    for (int kp = 0; kp < kn; kp++) {
        int k = k0 + kp;
        bool Lprev = (ELL >= 3) && (k == K);
        bool Rprev = (ELL >= 3) && (k == 1);
        if (!Lprev && side == 0) rowL[kp][u] = ws[chIdx(k - 1, s, b) + u];
        if (!Rprev && side == 1) rowR[kp][u] = ws[chIdx(ELL - k - 1, s + k, b) + u];
    }
    // recon prev-level rows from partials (block-uniform conditions)
    for (int kp = 0; kp < kn; kp++) {
        int k = k0 + kp;
        if ((ELL >= 3) && (k == K)) reconRow(&rowL[kp][0], ws, prevS, prevM, s * 8 + b, KCp, res2all);
        if ((ELL >= 3) && (k == 1)) reconRow(&rowR[kp][0], ws, prevS, prevM, (s + 1) * 8 + b, KCp, res2all);
    }
    __syncthreads();

    // 2. MERGED region (read-only on rows): per-k row maxes + raw argpc gather to registers
    int w = t >> 6, lane = t & 63;
    if (w < 2 * kn) {
        int kp = w >> 1;
        const float* pr = (w & 1) ? &rowR[kp][0] : &rowL[kp][0];
        float v = fmaxf(fmaxf(pr[lane], pr[lane + 64]), fmaxf(pr[lane + 128], pr[lane + 192]));
        v = waveMax(v);
        if (lane == 0) { if (w & 1) mRs[kp] = v; else mLs[kp] = v; }
    }
    int kp3 = t >> 7, jj3 = t & 127;
    bool g3a = (jj3 < 48) && (kp3 < kn);
    bool g3b = (jj3 >= 64 && jj3 < 112) && (kp3 < kn);
    float rawB = 0.f;
    if (g3a)      rawB = rowR[kp3][argpc[j0 + jj3]];
    else if (g3b) rawB = rowL[kp3][argpc[j0 + jj3 - 64]];
    __syncthreads();
    float mc = -3.0e38f;
    for (int kp = 0; kp < kn; kp++) mc = fmaxf(mc, mLs[kp] + mRs[kp]);

    // 3. MERGED exp phase: write eB from registers AND exponentiate rows in place.
    if (g3a)      eB0[kp3][jj3]      = expf(rawB - (mc - mLs[kp3]));
    else if (g3b) eB1[kp3][jj3 - 64] = expf(rawB - (mc - mRs[kp3]));
    for (int kp = 0; kp < kn; kp++) {
        if (side == 0) rowL[kp][u] = expf(rowL[kp][u] - mLs[kp]);
        else           rowR[kp][u] = expf(rowR[kp][u] - mRs[kp]);
    }
    __syncthreads();

    // 4. accumulate: sub = which*2 + jh24; 24 j per group, kn k's
    int r = t & 127, sub = t >> 7;
    int which = sub >> 1;
    int jbase = (sub & 1) * 24;
    const float* eGT = ws + (which == 0 ? OFF_EGR : OFF_EGL);
    const int* idxT = ((const int*)ws) + (which == 0 ? OFF_LF : OFF_RF);
    const float (*gA)[256] = which ? rowR : rowL;
    const float (*gB)[48]  = which ? eB1 : eB0;
    float acc = 0.f;
    for (int jc = 0; jc < 24; jc += 4) {
        int jj = jbase + jc;
        int j = j0 + jj;
        float g0 = eGT[(size_t)(j + 0) * QRES + r];
        float g1 = eGT[(size_t)(j + 1) * QRES + r];
        float g2 = eGT[(size_t)(j + 2) * QRES + r];
        float g3 = eGT[(size_t)(j + 3) * QRES + r];
        int i0 = idxT[(size_t)(j + 0) * QRES + r];
        int i1 = idxT[(size_t)(j + 1) * QRES + r];
        int i2 = idxT[(size_t)(j + 2) * QRES + r];
        int i3 = idxT[(size_t)(j + 3) * QRES + r];
        float t0 = 0.f, t1 = 0.f, t2 = 0.f, t3 = 0.f;
        for (int kp = 0; kp < kn; kp++) {
            const float* gs = gA[kp];
            float4 e4 = *(const float4*)&gB[kp][jj];
            t0 += gs[i0] * e4.x;
            t1 += gs[i1] * e4.y;
            t2 += gs[i2] * e4.z;
            t3 += gs[i3] * e4.w;
        }
        acc += g0 * t0 + g1 * t1 + g2 * t2 + g3 * t3;
    }
    Sred[t] = acc;
    __syncthreads();
    if (t < QRES) {
        float S = Sred[t] + Sred[128 + t] + Sred[256 + t] + Sred[384 + t];
        ws[curS + (size_t)aid * QRES + t] = S;
    }
    if (t == 0) ws[curM + aid] = mc;
}

// ---------------- root: reconstruct final row from level-16 partials, then lse ----------------
__global__ __launch_bounds__(256) void root_kernel(const float* __restrict__ root_w,
                                                   const float* __restrict__ root_b,
                                                   const float* __restrict__ ws,
                                                   const int* __restrict__ res2all,
                                                   float* __restrict__ out) {
    int b = blockIdx.x, t = threadIdx.x;
    __shared__ float scr[4];
    __shared__ float outrow[256];
    {
        int np = JS * 4;     // ell=16: KC=4, parity 0
        size_t base = (size_t)b * np;
        outrow[t] = NEGV;
        float M = -3.0e38f;
        for (int p = 0; p < np; p++) M = fmaxf(M, ws[OFF_P0M + base + p]);
        __syncthreads();
        if (t < QRES) {
            float S = 0.f;
            for (int p = 0; p < np; p++)
                S += expf(ws[OFF_P0M + base + p] - M) * ws[OFF_P0S + (base + p) * QRES + t];
            outrow[res2all[t]] = logf(S) + M + ws[OFF_S0 + res2all[t]];
        }
        __syncthreads();
    }
    float rv = root_w[t] + root_b[t];
    float mroot = blockMax(rv, scr, 4);
    float sroot = blockSum(expf(rv - mroot), scr, 4);
    float lroot = mroot + logf(sroot);
    float v = outrow[t] + rv - lroot;
    float m2 = blockMax(v, scr, 4);
    float s2 = blockSum(expf(v - m2), scr, 4);
    if (t == 0) out[b] = m2 + logf(s2);
}

template<int ELL>
static inline void launch_level(float* ws, const int* argpc, const int* res2all,
                                hipStream_t stream) {
    constexpr int n = T_ - ELL + 1;
    constexpr int K = ELL - 1, KC = (K + 3) / 4;
    constexpr int matCount = (ELL >= 3) ? (n + 1) * 8 : 0;
    constexpr int accCount = n * 8 * JS * KC;
    level_k<ELL><<<dim3(matCount + accCount), dim3(512), 0, stream>>>(ws, argpc, res2all);
}

extern "C" void kernel_launch(void* const* d_in, const int* in_sizes, int n_in,
                              void* d_out, int out_size, void* d_ws, size_t ws_size,
                              hipStream_t stream) {
    const int*   words   = (const int*)  d_in[0];
    const float* nt_emb  = (const float*)d_in[1];
    const float* W_emit  = (const float*)d_in[2];
    const float* b_emit  = (const float*)d_in[3];
    const float* rule_W  = (const float*)d_in[4];
    const float* rule_b  = (const float*)d_in[5];
    const float* assoc   = (const float*)d_in[6];
    const float* root_w  = (const float*)d_in[7];
    const float* root_b  = (const float*)d_in[8];
    const float* sw1     = (const float*)d_in[9];
    const float* sb1     = (const float*)d_in[10];
    const float* r1w1    = (const float*)d_in[11];
    const float* r1b1    = (const float*)d_in[12];
    const float* r1w2    = (const float*)d_in[13];
    const float* r1b2    = (const float*)d_in[14];
    const float* r2w1    = (const float*)d_in[15];
    const float* r2b1    = (const float*)d_in[16];
    const float* r2w2    = (const float*)d_in[17];
    const float* r2b2    = (const float*)d_in[18];
    const float* sw2     = (const float*)d_in[19];
    const float* sb2     = (const float*)d_in[20];
    const int*   lfunc   = (const int*)  d_in[21];
    const int*   rfunc   = (const int*)  d_in[22];
    const int*   argpc   = (const int*)  d_in[23];
    const int*   res2all = (const int*)  d_in[24];
    const float* larg_m  = (const float*)d_in[25];
    const float* rarg_m  = (const float*)d_in[26];
    float* ws  = (float*)d_ws;
    float* out = (float*)d_out;

    prep_g_kernel<<<dim3(QRES), dim3(QARG), 0, stream>>>(rule_W, rule_b, assoc, larg_m, rarg_m,
                                                         lfunc, rfunc, ws);
    mlp_kernel<<<dim3(QALL), dim3(1024), 0, stream>>>(nt_emb, sw1, sb1, r1w1, r1b1, r1w2, r1b2,
                                                      r2w1, r2b1, r2w2, r2b2, sw2, sb2, ws);
    emit_kernel<<<dim3(NWT, QALL / 64), dim3(256), 0, stream>>>(words, nt_emb, W_emit, b_emit, ws);
    lse_kernel<<<dim3(QALL), dim3(256), 0, stream>>>(ws);
    chart0_kernel<<<dim3(B_ * T_), dim3(256), 0, stream>>>(ws);

    launch_level<2>(ws, argpc, res2all, stream);
    launch_level<3>(ws, argpc, res2all, stream);
    launch_level<4>(ws, argpc, res2all, stream);
    launch_level<5>(ws, argpc, res2all, stream);
    launch_level<6>(ws, argpc, res2all, stream);
    launch_level<7>(ws, argpc, res2all, stream);
    launch_level<8>(ws, argpc, res2all, stream);
    launch_level<9>(ws, argpc, res2all, stream);
    launch_level<10>(ws, argpc, res2all, stream);
    launch_level<11>(ws, argpc, res2all, stream);
    launch_level<12>(ws, argpc, res2all, stream);
    launch_level<13>(ws, argpc, res2all, stream);
    launch_level<14>(ws, argpc, res2all, stream);
    launch_level<15>(ws, argpc, res2all, stream);
    launch_level<16>(ws, argpc, res2all, stream);

    root_kernel<<<dim3(B_), dim3(256), 0, stream>>>(root_w, root_b, ws, res2all, out);
}

// Round 18
// 330.117 us; speedup vs baseline: 1.0242x; 1.0242x over previous
//
#include <hip/hip_runtime.h>
#include <math.h>

#define NEGV -10000000.0f

constexpr int B_ = 8, T_ = 16;
constexpr int QALL = 256, QRES = 128, QARG = 192;
constexpr int STATE = 256, VOCAB = 10000;
constexpr int WT = 64;
constexpr int NWT = (VOCAB + WT - 1) / WT;   // 157
constexpr int JS = 4;                        // DP j-split (4 x 48-j windows)

// ---- workspace layout (units of 4 bytes) ----
constexpr size_t OFF_CHART = 0;                                    // chart[ell][s][b][a]
constexpr size_t CHART_SZ  = (size_t)T_ * T_ * B_ * QALL;          // 524288
constexpr size_t OFF_EGR   = OFF_CHART + CHART_SZ;                 // exp(G_rarg) [j][r]
constexpr size_t OFF_EGL   = OFF_EGR + (size_t)QARG * QRES;        // exp(G_larg) [j][r]
constexpr size_t OFF_LF    = OFF_EGL + (size_t)QARG * QRES;        // lfunc transposed [j][r] (int)
constexpr size_t OFF_RF    = OFF_LF + (size_t)QARG * QRES;         // rfunc transposed [j][r] (int)
constexpr size_t OFF_S0    = OFF_RF + (size_t)QARG * QRES;         // split[:,0] per a (256)
constexpr size_t OFF_S1    = OFF_S0 + QALL;                        // split[:,1] per a (256)
constexpr size_t OFF_LSE   = OFF_S1 + QALL;                        // emit row lse (256)
constexpr size_t OFF_PMIT  = OFF_LSE + QALL;                       // emit partial max [wt][a]
constexpr size_t OFF_PSEM  = OFF_PMIT + (size_t)NWT * QALL;        // emit partial sum [wt][a]
// DP partial ping-pong buffers OVERLAY the emit PM/PS region (dead after chart0).
constexpr int    PMAXP     = 704;
constexpr size_t OFF_P0S   = OFF_PMIT;                             // [704][128]
constexpr size_t OFF_P0M   = OFF_P0S + (size_t)PMAXP * QRES;       // [704]
constexpr size_t OFF_P1S   = OFF_P0M + PMAXP;
constexpr size_t OFF_P1M   = OFF_P1S + (size_t)PMAXP * QRES;
// raw emit scores for the 128 word positions [i][a]; dead after chart0, so it
// overlays the P1 buffer (P1 first written at ell=3, after chart0 completes).
// NWT=157: PM/PS ends at OFF_PMIT+80384 < OFF_P1S (+90816) -> overlay is safe.
constexpr size_t OFF_RAW   = OFF_P1S;                              // [128][256]

__device__ __forceinline__ size_t chIdx(int ell, int s, int b) {
    return OFF_CHART + ((size_t)((ell * 16 + s) * 8 + b)) * 256;
}

__device__ __forceinline__ float waveMax(float v) {
    #pragma unroll
    for (int m = 32; m >= 1; m >>= 1) v = fmaxf(v, __shfl_xor(v, m, 64));
    return v;
}
__device__ __forceinline__ float waveSum(float v) {
    #pragma unroll
    for (int m = 32; m >= 1; m >>= 1) v += __shfl_xor(v, m, 64);
    return v;
}
__device__ __forceinline__ float blockMax(float v, float* scr, int nw) {
    int lane = threadIdx.x & 63, w = threadIdx.x >> 6;
    v = waveMax(v);
    if (lane == 0) scr[w] = v;
    __syncthreads();
    float r = scr[0];
    for (int i = 1; i < nw; i++) r = fmaxf(r, scr[i]);
    __syncthreads();
    return r;
}
__device__ __forceinline__ float blockSum(float v, float* scr, int nw) {
    int lane = threadIdx.x & 63, w = threadIdx.x >> 6;
    v = waveSum(v);
    if (lane == 0) scr[w] = v;
    __syncthreads();
    float r = 0.f;
    for (int i = 0; i < nw; i++) r += scr[i];
    __syncthreads();
    return r;
}

// ---------------- G tables ----------------
__global__ __launch_bounds__(192) void prep_g_kernel(
        const float* __restrict__ rule_W, const float* __restrict__ rule_b,
        const float* __restrict__ assoc,
        const float* __restrict__ larg_mask, const float* __restrict__ rarg_mask,
        const int* __restrict__ lfunc, const int* __restrict__ rfunc,
        float* __restrict__ ws) {
    __shared__ float scr[4];
    int r = blockIdx.x;      // 0..127
    int j = threadIdx.x;     // 0..191
    float v0 = rule_W[r * 2 * QARG + j] + rule_b[j];
    float v1 = rule_W[r * 2 * QARG + QARG + j] + rule_b[QARG + j];
    float m = blockMax(fmaxf(v0, v1), scr, 3);
    float s = blockSum(expf(v0 - m) + expf(v1 - m), scr, 3);
    float l = m + logf(s);
    float av = assoc[r * QARG + j];
    float gl = v0 - l + av + larg_mask[r * QARG + j];
    float gr = v1 - l + av + rarg_mask[r * QARG + j];
    ws[OFF_EGL + (size_t)j * QRES + r] = expf(gl);
    ws[OFF_EGR + (size_t)j * QRES + r] = expf(gr);
    ((int*)ws)[OFF_LF + (size_t)j * QRES + r] = lfunc[r * QARG + j];
    ((int*)ws)[OFF_RF + (size_t)j * QRES + r] = rfunc[r * QARG + j];
}

// ---------------- split-score MLP (1024 threads, split-K x4) ----------------
#define MLP_MATVEC(INBUF, W, RES) do {                                          \
    float acc_ = 0.f;                                                           \
    _Pragma("unroll 16")                                                        \
    for (int s_ = 0; s_ < 64; s_++)                                             \
        acc_ += INBUF[s0 + s_] * W[(s0 + s_) * STATE + col];                    \
    part[t] = acc_;                                                             \
    __syncthreads();                                                            \
    RES = part[col] + part[STATE + col] + part[2 * STATE + col]                 \
        + part[3 * STATE + col];                                                \
} while (0)

__global__ __launch_bounds__(1024) void mlp_kernel(
        const float* __restrict__ nt_emb,
        const float* __restrict__ sw1, const float* __restrict__ sb1,
        const float* __restrict__ r1w1, const float* __restrict__ r1b1,
        const float* __restrict__ r1w2, const float* __restrict__ r1b2,
        const float* __restrict__ r2w1, const float* __restrict__ r2b1,
        const float* __restrict__ r2w2, const float* __restrict__ r2b2,
        const float* __restrict__ sw2, const float* __restrict__ sb2,
        float* __restrict__ ws) {
    __shared__ float xin[STATE], hbuf[STATE], tbuf[STATE];
    __shared__ float part[4 * STATE];
    __shared__ float scr[16];
    int a = blockIdx.x, t = threadIdx.x;
    int col = t & 255;
    int grp = t >> 8;
    int s0 = grp * 64;
    if (t < STATE) xin[t] = nt_emb[a * STATE + t];
    __syncthreads();
    float r;
    MLP_MATVEC(xin, sw1, r);
    if (grp == 0) hbuf[col] = r + sb1[col];
    __syncthreads();
    MLP_MATVEC(hbuf, r1w1, r);
    if (grp == 0) tbuf[col] = fmaxf(r + r1b1[col], 0.f);
    __syncthreads();
    MLP_MATVEC(tbuf, r1w2, r);
    if (grp == 0) hbuf[col] += fmaxf(r + r1b2[col], 0.f);
    __syncthreads();
    MLP_MATVEC(hbuf, r2w1, r);
    if (grp == 0) tbuf[col] = fmaxf(r + r2b1[col], 0.f);
    __syncthreads();
    MLP_MATVEC(tbuf, r2w2, r);
    if (grp == 0) hbuf[col] += fmaxf(r + r2b2[col], 0.f);
    __syncthreads();
    float hv = (t < STATE) ? hbuf[t] : 0.f;
    float v0 = (t < STATE) ? hv * sw2[t * 2 + 0] : 0.f;
    float v1 = (t < STATE) ? hv * sw2[t * 2 + 1] : 0.f;
    float u0 = blockSum(v0, scr, 16) + sb2[0];
    float u1 = blockSum(v1, scr, 16) + sb2[1];
    if (t == 0) {
        float mm = fmaxf(u0, u1);
        float l = mm + logf(expf(u0 - mm) + expf(u1 - mm));
        ws[OFF_S0 + a] = u0 - l;
        ws[OFF_S1 + a] = u1 - l;
    }
}

// ---------------- emit GEMM: double-buffered LDS + register prefetch (WT=64 optimum) ----------------
__global__ __launch_bounds__(256) void emit_kernel(
        const int* __restrict__ words,
        const float* __restrict__ nt_emb, const float* __restrict__ W_emit,
        const float* __restrict__ b_emit, float* __restrict__ ws) {
    __shared__ float As[2][16][64];     // [buf][kk][aa]
    __shared__ float Bs[2][16][64];     // [buf][kk][ww]
    __shared__ float redM[64][16], redS[64][16];
    __shared__ int sw[128];
    int wt = blockIdx.x, at = blockIdx.y;
    int t = threadIdx.x;
    int tx = t & 15, ty = t >> 4;
    if (t < 128) sw[t] = words[t];
    int wbase = wt * WT, abase = at * 64;
    int idx = t * 4;
    int akk = idx & 15, aaa = idx >> 4;      // A staging coords (akk multiple of 4)
    int bkk = idx >> 6, bww = idx & 63;      // B staging coords (bww multiple of 4)
    const float* Aptr = &nt_emb[(size_t)(abase + aaa) * STATE + akk];
    int bw = wbase + bww;
    bool bfull = (bw + 3 < VOCAB);

    // prologue: stage k-tile 0 into buffer 0
    {
        float4 av = *(const float4*)(Aptr + 0);
        float4 bv;
        const float* src = &W_emit[(size_t)bkk * VOCAB + bw];
        if (bfull) bv = *(const float4*)src;
        else {
            float tv[4];
            #pragma unroll
            for (int q = 0; q < 4; q++) tv[q] = (bw + q < VOCAB) ? src[q] : 0.f;
            bv = make_float4(tv[0], tv[1], tv[2], tv[3]);
        }
        As[0][akk + 0][aaa] = av.x; As[0][akk + 1][aaa] = av.y;
        As[0][akk + 2][aaa] = av.z; As[0][akk + 3][aaa] = av.w;
        *(float4*)&Bs[0][bkk][bww] = bv;
    }
    __syncthreads();

    float acc[4][4];
    #pragma unroll
    for (int i = 0; i < 4; i++)
        #pragma unroll
        for (int j = 0; j < 4; j++) acc[i][j] = 0.f;

    for (int step = 0; step < 16; step++) {
        int cur = step & 1;
        float4 nav, nbv;
        bool more = (step + 1 < 16);
        if (more) {   // issue next-tile loads BEFORE compute (hide latency)
            nav = *(const float4*)(Aptr + (step + 1) * 16);
            const float* src = &W_emit[(size_t)((step + 1) * 16 + bkk) * VOCAB + bw];
            if (bfull) nbv = *(const float4*)src;
            else {
                float tv[4];
                #pragma unroll
                for (int q = 0; q < 4; q++) tv[q] = (bw + q < VOCAB) ? src[q] : 0.f;
                nbv = make_float4(tv[0], tv[1], tv[2], tv[3]);
            }
        }
        #pragma unroll
        for (int kk = 0; kk < 16; kk++) {
            float a4[4], b4[4];
            #pragma unroll
            for (int i = 0; i < 4; i++) a4[i] = As[cur][kk][ty * 4 + i];
            #pragma unroll
            for (int j = 0; j < 4; j++) b4[j] = Bs[cur][kk][tx * 4 + j];
            #pragma unroll
            for (int i = 0; i < 4; i++)
                #pragma unroll
                for (int j = 0; j < 4; j++) acc[i][j] += a4[i] * b4[j];
        }
        if (more) {
            int nb = cur ^ 1;
            As[nb][akk + 0][aaa] = nav.x; As[nb][akk + 1][aaa] = nav.y;
            As[nb][akk + 2][aaa] = nav.z; As[nb][akk + 3][aaa] = nav.w;
            *(float4*)&Bs[nb][bkk][bww] = nbv;
        }
        __syncthreads();
    }

    // epilogue: + b_emit
    float be[4];
    #pragma unroll
    for (int j = 0; j < 4; j++) {
        int w = wbase + tx * 4 + j;
        be[j] = (w < VOCAB) ? b_emit[w] : 0.f;
    }
    #pragma unroll
    for (int i = 0; i < 4; i++)
        #pragma unroll
        for (int j = 0; j < 4; j++) {
            int w = wbase + tx * 4 + j;
            if (w < VOCAB) acc[i][j] += be[j];
        }
    // capture word columns: raw[i2][a] = score(a, words[i2]) for words in this tile
    for (int i2 = 0; i2 < 128; i2++) {
        int loc = sw[i2] - wbase;
        if (loc >= 0 && loc < WT && (loc >> 2) == tx) {
            int j = loc & 3;
            #pragma unroll
            for (int i = 0; i < 4; i++)
                ws[OFF_RAW + (size_t)i2 * QALL + abase + ty * 4 + i] = acc[i][j];
        }
    }
    // per-row partial (max, sumexp) over the 64 w of this tile
    #pragma unroll
    for (int i = 0; i < 4; i++) {
        float mloc = -3.0e38f;
        #pragma unroll
        for (int j = 0; j < 4; j++) {
            int w = wbase + tx * 4 + j;
            if (w < VOCAB) mloc = fmaxf(mloc, acc[i][j]);
        }
        float sloc = 0.f;
        #pragma unroll
        for (int j = 0; j < 4; j++) {
            int w = wbase + tx * 4 + j;
            if (w < VOCAB) sloc += expf(acc[i][j] - mloc);
        }
        redM[ty * 4 + i][tx] = mloc;
        redS[ty * 4 + i][tx] = sloc;
    }
    __syncthreads();
    if (t < 64) {
        float M = -3.0e38f;
        #pragma unroll
        for (int i = 0; i < 16; i++) M = fmaxf(M, redM[t][i]);
        float S = 0.f;
        #pragma unroll
        for (int i = 0; i < 16; i++) S += redS[t][i] * expf(redM[t][i] - M);
        ws[OFF_PMIT + (size_t)wt * QALL + abase + t] = M;
        ws[OFF_PSEM + (size_t)wt * QALL + abase + t] = S;
    }
}

// ---------------- combine emit partials -> lse per row (parallel: one block per a) ----------------
__global__ __launch_bounds__(256) void lse_kernel(float* __restrict__ ws) {
    __shared__ float scr[4];
    int a = blockIdx.x;
    int t = threadIdx.x;
    float myM = -3.0e38f;
    if (t < NWT) myM = ws[OFF_PMIT + (size_t)t * QALL + a];
    float M = blockMax(myM, scr, 4);
    float myS = 0.f;
    if (t < NWT) myS = ws[OFF_PSEM + (size_t)t * QALL + a] * expf(myM - M);
    float S = blockSum(myS, scr, 4);
    if (t == 0) ws[OFF_LSE + a] = M + logf(S);
}

// ---------------- chart level 0: trivial assemble from captured raw scores ----------------
__global__ __launch_bounds__(256) void chart0_kernel(float* __restrict__ ws) {
    int blk = blockIdx.x;            // i2 = b*16 + tp
    int b = blk >> 4, tp = blk & 15;
    int a = threadIdx.x;
    float val = ws[OFF_RAW + (size_t)blk * QALL + a] - ws[OFF_LSE + a] + ws[OFF_S1 + a];
    ws[chIdx(0, tp, b) + a] = val;
}

// ---------------- per-level DP (templated on ELL; 4 main barriers, merged gather) ----------------
__device__ __forceinline__ void reconRow(float* row, const float* __restrict__ ws,
                                         size_t prevS, size_t prevM, int cellp, int KCp,
                                         const int* __restrict__ res2all) {
    int t = threadIdx.x;
    int np = JS * KCp;
    size_t base = (size_t)cellp * np;
    if (t < 256) row[t] = NEGV;
    float M = -3.0e38f;
    for (int p = 0; p < np; p++) M = fmaxf(M, ws[prevM + base + p]);
    __syncthreads();
    if (t < QRES) {
        float S = 0.f;
        for (int p = 0; p < np; p++)
            S += expf(ws[prevM + base + p] - M) * ws[prevS + (base + p) * QRES + t];
        row[res2all[t]] = logf(S) + M + ws[OFF_S0 + res2all[t]];
    }
    __syncthreads();
}

template<int ELL>
__global__ __launch_bounds__(512) void level_k(float* __restrict__ ws,
                                               const int* __restrict__ argpc,
                                               const int* __restrict__ res2all) {
    __shared__ __align__(16) float rowL[4][256], rowR[4][256];
    __shared__ __align__(16) float eB0[4][48], eB1[4][48];
    __shared__ float mLs[4], mRs[4];
    __shared__ float Sred[512];
    __shared__ float outrow[256];

    constexpr int K = ELL - 1;
    constexpr int KC = (K + 3) >> 2;
    constexpr int matCount = (ELL >= 3) ? (T_ - ELL + 2) * 8 : 0;
    constexpr int ellp = ELL - 1;
    constexpr int KCp = (ellp - 1 + 3) >> 2;
    constexpr size_t prevS = (ellp & 1) ? OFF_P1S : OFF_P0S;
    constexpr size_t prevM = (ellp & 1) ? OFF_P1M : OFF_P0M;
    constexpr size_t curS  = (ELL & 1) ? OFF_P1S : OFF_P0S;
    constexpr size_t curM  = (ELL & 1) ? OFF_P1M : OFF_P0M;

    int t = threadIdx.x;
    int bid = blockIdx.x;

    if (bid < matCount) {
        int cellp = bid;
        int sp = cellp >> 3, bp = cellp & 7;
        reconRow(outrow, ws, prevS, prevM, cellp, KCp, res2all);
        if (t < 256) ws[chIdx(ellp - 1, sp, bp) + t] = outrow[t];
        return;
    }

    int aid = bid - matCount;          // aid = ((cell*JS + jq)*KC + kc)
    int kc = aid % KC;
    int rem = aid / KC;
    int jq = rem & (JS - 1);
    int cell = rem >> 2;
    int s = cell >> 3, b = cell & 7;
    int k0 = kc * 4 + 1;
    int kn = min(4, K - kc * 4);
    int j0 = jq * 48;
    int side = t >> 8, u = t & 255;

    // 1. bulk-load materialized rows
    for (int kp = 0; kp < kn; kp++) {
        int k = k0 + kp;
        bool Lprev = (ELL >= 3) && (k == K);
        bool Rprev = (ELL >= 3) && (k == 1);
        if (!Lprev && side == 0) rowL[kp][u] = ws[chIdx(k - 1, s, b) + u];
        if (!Rprev && side == 1) rowR[kp][u] = ws[chIdx(ELL - k - 1, s + k, b) + u];
    }
    // recon prev-level rows from partials (block-uniform conditions)
    for (int kp = 0; kp < kn; kp++) {
        int k = k0 + kp;
        if ((ELL >= 3) && (k == K)) reconRow(&rowL[kp][0], ws, prevS, prevM, s * 8 + b, KCp, res2all);
        if ((ELL >= 3) && (k == 1)) reconRow(&rowR[kp][0], ws, prevS, prevM, (s + 1) * 8 + b, KCp, res2all);
    }
    __syncthreads();

    // 2. MERGED region (read-only on rows): per-k row maxes + raw argpc gather to registers
    int w = t >> 6, lane = t & 63;
    if (w < 2 * kn) {
        int kp = w >> 1;
        const float* pr = (w & 1) ? &rowR[kp][0] : &rowL[kp][0];
        float v = fmaxf(fmaxf(pr[lane], pr[lane + 64]), fmaxf(pr[lane + 128], pr[lane + 192]));
        v = waveMax(v);
        if (lane == 0) { if (w & 1) mRs[kp] = v; else mLs[kp] = v; }
    }
    int kp3 = t >> 7, jj3 = t & 127;
    bool g3a = (jj3 < 48) && (kp3 < kn);
    bool g3b = (jj3 >= 64 && jj3 < 112) && (kp3 < kn);
    float rawB = 0.f;
    if (g3a)      rawB = rowR[kp3][argpc[j0 + jj3]];
    else if (g3b) rawB = rowL[kp3][argpc[j0 + jj3 - 64]];
    __syncthreads();
    float mc = -3.0e38f;
    for (int kp = 0; kp < kn; kp++) mc = fmaxf(mc, mLs[kp] + mRs[kp]);

    // 3. MERGED exp phase: write eB from registers AND exponentiate rows in place.
    if (g3a)      eB0[kp3][jj3]      = expf(rawB - (mc - mLs[kp3]));
    else if (g3b) eB1[kp3][jj3 - 64] = expf(rawB - (mc - mRs[kp3]));
    for (int kp = 0; kp < kn; kp++) {
        if (side == 0) rowL[kp][u] = expf(rowL[kp][u] - mLs[kp]);
        else           rowR[kp][u] = expf(rowR[kp][u] - mRs[kp]);
    }
    __syncthreads();

    // 4. accumulate: sub = which*2 + jh24; 24 j per group, kn k's
    int r = t & 127, sub = t >> 7;
    int which = sub >> 1;
    int jbase = (sub & 1) * 24;
    const float* eGT = ws + (which == 0 ? OFF_EGR : OFF_EGL);
    const int* idxT = ((const int*)ws) + (which == 0 ? OFF_LF : OFF_RF);
    const float (*gA)[256] = which ? rowR : rowL;
    const float (*gB)[48]  = which ? eB1 : eB0;
    float acc = 0.f;
    for (int jc = 0; jc < 24; jc += 4) {
        int jj = jbase + jc;
        int j = j0 + jj;
        float g0 = eGT[(size_t)(j + 0) * QRES + r];
        float g1 = eGT[(size_t)(j + 1) * QRES + r];
        float g2 = eGT[(size_t)(j + 2) * QRES + r];
        float g3 = eGT[(size_t)(j + 3) * QRES + r];
        int i0 = idxT[(size_t)(j + 0) * QRES + r];
        int i1 = idxT[(size_t)(j + 1) * QRES + r];
        int i2 = idxT[(size_t)(j + 2) * QRES + r];
        int i3 = idxT[(size_t)(j + 3) * QRES + r];
        float t0 = 0.f, t1 = 0.f, t2 = 0.f, t3 = 0.f;
        for (int kp = 0; kp < kn; kp++) {
            const float* gs = gA[kp];
            float4 e4 = *(const float4*)&gB[kp][jj];
            t0 += gs[i0] * e4.x;
            t1 += gs[i1] * e4.y;
            t2 += gs[i2] * e4.z;
            t3 += gs[i3] * e4.w;
        }
        acc += g0 * t0 + g1 * t1 + g2 * t2 + g3 * t3;
    }
    Sred[t] = acc;
    __syncthreads();
    if (t < QRES) {
        float S = Sred[t] + Sred[128 + t] + Sred[256 + t] + Sred[384 + t];
        ws[curS + (size_t)aid * QRES + t] = S;
    }
    if (t == 0) ws[curM + aid] = mc;
}

// ---------------- root: reconstruct final row from level-16 partials, then lse ----------------
__global__ __launch_bounds__(256) void root_kernel(const float* __restrict__ root_w,
                                                   const float* __restrict__ root_b,
                                                   const float* __restrict__ ws,
                                                   const int* __restrict__ res2all,
                                                   float* __restrict__ out) {
    int b = blockIdx.x, t = threadIdx.x;
    __shared__ float scr[4];
    __shared__ float outrow[256];
    {
        int np = JS * 4;     // ell=16: KC=4, parity 0
        size_t base = (size_t)b * np;
        outrow[t] = NEGV;
        float M = -3.0e38f;
        for (int p = 0; p < np; p++) M = fmaxf(M, ws[OFF_P0M + base + p]);
        __syncthreads();
        if (t < QRES) {
            float S = 0.f;
            for (int p = 0; p < np; p++)
                S += expf(ws[OFF_P0M + base + p] - M) * ws[OFF_P0S + (base + p) * QRES + t];
            outrow[res2all[t]] = logf(S) + M + ws[OFF_S0 + res2all[t]];
        }
        __syncthreads();
    }
    float rv = root_w[t] + root_b[t];
    float mroot = blockMax(rv, scr, 4);
    float sroot = blockSum(expf(rv - mroot), scr, 4);
    float lroot = mroot + logf(sroot);
    float v = outrow[t] + rv - lroot;
    float m2 = blockMax(v, scr, 4);
    float s2 = blockSum(expf(v - m2), scr, 4);
    if (t == 0) out[b] = m2 + logf(s2);
}

template<int ELL>
static inline void launch_level(float* ws, const int* argpc, const int* res2all,
                                hipStream_t stream) {
    constexpr int n = T_ - ELL + 1;
    constexpr int K = ELL - 1, KC = (K + 3) / 4;
    constexpr int matCount = (ELL >= 3) ? (n + 1) * 8 : 0;
    constexpr int accCount = n * 8 * JS * KC;
    level_k<ELL><<<dim3(matCount + accCount), dim3(512), 0, stream>>>(ws, argpc, res2all);
}

extern "C" void kernel_launch(void* const* d_in, const int* in_sizes, int n_in,
                              void* d_out, int out_size, void* d_ws, size_t ws_size,
                              hipStream_t stream) {
    const int*   words   = (const int*)  d_in[0];
    const float* nt_emb  = (const float*)d_in[1];
    const float* W_emit  = (const float*)d_in[2];
    const float* b_emit  = (const float*)d_in[3];
    const float* rule_W  = (const float*)d_in[4];
    const float* rule_b  = (const float*)d_in[5];
    const float* assoc   = (const float*)d_in[6];
    const float* root_w  = (const float*)d_in[7];
    const float* root_b  = (const float*)d_in[8];
    const float* sw1     = (const float*)d_in[9];
    const float* sb1     = (const float*)d_in[10];
    const float* r1w1    = (const float*)d_in[11];
    const float* r1b1    = (const float*)d_in[12];
    const float* r1w2    = (const float*)d_in[13];
    const float* r1b2    = (const float*)d_in[14];
    const float* r2w1    = (const float*)d_in[15];
    const float* r2b1    = (const float*)d_in[16];
    const float* r2w2    = (const float*)d_in[17];
    const float* r2b2    = (const float*)d_in[18];
    const float* sw2     = (const float*)d_in[19];
    const float* sb2     = (const float*)d_in[20];
    const int*   lfunc   = (const int*)  d_in[21];
    const int*   rfunc   = (const int*)  d_in[22];
    const int*   argpc   = (const int*)  d_in[23];
    const int*   res2all = (const int*)  d_in[24];
    const float* larg_m  = (const float*)d_in[25];
    const float* rarg_m  = (const float*)d_in[26];
    float* ws  = (float*)d_ws;
    float* out = (float*)d_out;

    prep_g_kernel<<<dim3(QRES), dim3(QARG), 0, stream>>>(rule_W, rule_b, assoc, larg_m, rarg_m,
                                                         lfunc, rfunc, ws);
    mlp_kernel<<<dim3(QALL), dim3(1024), 0, stream>>>(nt_emb, sw1, sb1, r1w1, r1b1, r1w2, r1b2,
                                                      r2w1, r2b1, r2w2, r2b2, sw2, sb2, ws);
    emit_kernel<<<dim3(NWT, QALL / 64), dim3(256), 0, stream>>>(words, nt_emb, W_emit, b_emit, ws);
    lse_kernel<<<dim3(QALL), dim3(256), 0, stream>>>(ws);
    chart0_kernel<<<dim3(B_ * T_), dim3(256), 0, stream>>>(ws);

    launch_level<2>(ws, argpc, res2all, stream);
    launch_level<3>(ws, argpc, res2all, stream);
    launch_level<4>(ws, argpc, res2all, stream);
    launch_level<5>(ws, argpc, res2all, stream);
    launch_level<6>(ws, argpc, res2all, stream);
    launch_level<7>(ws, argpc, res2all, stream);
    launch_level<8>(ws, argpc, res2all, stream);
    launch_level<9>(ws, argpc, res2all, stream);
    launch_level<10>(ws, argpc, res2all, stream);
    launch_level<11>(ws, argpc, res2all, stream);
    launch_level<12>(ws, argpc, res2all, stream);
    launch_level<13>(ws, argpc, res2all, stream);
    launch_level<14>(ws, argpc, res2all, stream);
    launch_level<15>(ws, argpc, res2all, stream);
    launch_level<16>(ws, argpc, res2all, stream);

    root_kernel<<<dim3(B_), dim3(256), 0, stream>>>(root_w, root_b, ws, res2all, out);
}